// Round 4
// baseline (249.008 us; speedup 1.0000x reference)
//
#include <hip/hip_runtime.h>

typedef float  f4v  __attribute__((ext_vector_type(4)));
typedef short  s8v  __attribute__((ext_vector_type(8)));

// fp32 -> bf16 round-to-nearest-even
__device__ __forceinline__ ushort f2b(float f) {
    union { float f; unsigned int u; } v; v.f = f;
    unsigned int u = v.u;
    u += 0x7fffu + ((u >> 16) & 1u);
    return (ushort)(u >> 16);
}
__device__ __forceinline__ float b2f(ushort u) {
    union { unsigned int u; float f; } v; v.u = ((unsigned int)u) << 16;
    return v.f;
}

// async global->LDS, 16B per lane. ldsp MUST be wave-uniform; HW writes
// lane i's 16B at ldsp + i*16 (no per-lane scatter, no padding allowed).
__device__ __forceinline__ void async16(const ushort* g, ushort* ldsp) {
    __builtin_amdgcn_global_load_lds(
        (const __attribute__((address_space(1))) unsigned int*)g,
        (__attribute__((address_space(3))) unsigned int*)ldsp, 16, 0, 0);
}

// ------- cast x (fp32) -> bf16 + zero row-sum accumulator + zero fp32 output -------
// n4 = 2M float4s of x == exactly the float4 count of Out (4*2048*1024/4).
__global__ __launch_bounds__(256) void cast_f32_bf16(const float* __restrict__ in,
                                                     ushort* __restrict__ out,
                                                     float* __restrict__ l,
                                                     float* __restrict__ oz, int n4) {
    int i = blockIdx.x * 256 + threadIdx.x;
    if (i < 8192) l[i] = 0.f;   // 4 batches x 2048 rows
    if (i < n4) {
        float4 f = ((const float4*)in)[i];
        ushort4 o;
        o.x = f2b(f.x); o.y = f2b(f.y); o.z = f2b(f.z); o.w = f2b(f.w);
        ((ushort4*)out)[i] = o;
        float4 z; z.x = 0.f; z.y = 0.f; z.z = 0.f; z.w = 0.f;
        ((float4*)oz)[i] = z;   // pre-zero Out for gemm_pv's split-K atomics
    }
}

// ---------------- transpose W [1024x1024] fp32 -> Wt bf16 [out][in] ----------------
__global__ __launch_bounds__(256) void transpose_cast(const float* __restrict__ w0,
                                                      const float* __restrict__ w1,
                                                      const float* __restrict__ w2,
                                                      ushort* __restrict__ out) {
    __shared__ float tile[32][33];
    const float* W = (blockIdx.z == 0) ? w0 : (blockIdx.z == 1 ? w1 : w2);
    ushort* O = out + (size_t)blockIdx.z * (1024u * 1024u);
    int x0 = blockIdx.x * 32, y0 = blockIdx.y * 32;
    int tx = threadIdx.x, ty = threadIdx.y;
    for (int i = 0; i < 4; i++)
        tile[ty + i * 8][tx] = W[(size_t)(y0 + ty + i * 8) * 1024 + x0 + tx];
    __syncthreads();
    for (int i = 0; i < 4; i++)
        O[(size_t)(x0 + ty + i * 8) * 1024 + y0 + tx] = f2b(tile[tx][ty + i * 8]);
}

// ===================== shared pipeline macros (counted-vmcnt, 3-phase) =====================
// Both-sides XOR swizzle: global source col pre-swizzled (lc8 = (lane&7)^lr, row%8==lr),
// ds_read col swizzled by ^(l16&7). Linear LDS dest for global_load_lds.

#define RD_A4(buf_)                                                                   \
    _Pragma("unroll") for (int mi = 0; mi < 4; mi++)                                  \
    _Pragma("unroll") for (int s = 0; s < 2; s++)                                     \
        af[mi][s] = *(const s8v*)&(buf_)[(wm + mi * 16 + l16) * 64 +                  \
                                         (((s * 4 + quad) ^ (l16 & 7)) * 8)];

#define RD_B2(buf_, NI0_)                                                             \
    _Pragma("unroll") for (int j = 0; j < 2; j++)                                     \
    _Pragma("unroll") for (int s = 0; s < 2; s++)                                     \
        bf[j][s] = *(const s8v*)&(buf_)[(wn + ((NI0_) + j) * 16 + l16) * 64 +         \
                                        (((s * 4 + quad) ^ (l16 & 7)) * 8)];

#define MFMA16(NI0_)                                                                  \
    _Pragma("unroll") for (int mi = 0; mi < 4; mi++)                                  \
    _Pragma("unroll") for (int j = 0; j < 2; j++)                                     \
    _Pragma("unroll") for (int s = 0; s < 2; s++)                                     \
        acc[mi][(NI0_) + j] = __builtin_amdgcn_mfma_f32_16x16x32_bf16(                \
            af[mi][s], bf[j][s], acc[mi][(NI0_) + j], 0, 0, 0);

// ---------------- fused QKV projection: 256x192 tile, counted-vmcnt pipeline --------
// Grid 32m x 16n = 512 blocks = exactly 2 full CU-rounds. 8 waves 4m x 2n ->
// wave tile 64x96 (acc[4][6]). LDS 144 KiB: A 3-deep [256][64], B 2-deep [192][64].
// 3 phases x 16 MFMA per K-tile; boundary vmcnt(4) leaves A(t+2) in flight.
__global__ __launch_bounds__(512, 2) void gemm_qkv(const ushort* __restrict__ A,
                                                   const ushort* __restrict__ Wt,
                                                   ushort* __restrict__ q,
                                                   ushort* __restrict__ k,
                                                   ushort* __restrict__ vt) {
    constexpr int K = 1024;
    extern __shared__ ushort lds[];

    const int L = blockIdx.x;
    const int xcd = L & 7, idx = L >> 3;            // idx 0..63
    const int ci = xcd >> 1, cj = xcd & 1;          // chunk grid 4x2 over 32m x 16n
    const int mo = idx >> 3, no = idx & 7;
    const int m0 = (ci * 8 + mo) * 256;             // 0..8191
    const int n0 = (cj * 8 + no) * 192;             // 0..3071 (spans q|k|v columns)

    const int tid = threadIdx.x;
    const int w = tid >> 6, lane = tid & 63, quad = lane >> 4, l16 = lane & 15;
    const int wm = (w >> 1) * 64, wn = (w & 1) * 96;

    ushort* a0 = lds;                // A [256][64] = 16384 ushorts per buffer
    ushort* a1 = lds + 16384;
    ushort* a2 = lds + 32768;
    ushort* b0 = lds + 49152;        // B [192][64] = 12288 ushorts per buffer
    ushort* b1 = lds + 61440;        // total 73728 ushorts = 144 KiB

    const int lr = lane >> 3;
    const int lc8 = (lane & 7) ^ lr;
    const ushort* Ab = A  + (size_t)(m0 + w * 8 + lr) * K + lc8 * 8;
    const ushort* Bb = Wt + (size_t)(n0 + w * 8 + lr) * K + lc8 * 8;  // Wt = [3072][1024]
    const int dW = w * 512;

#define ISSUE_A(buf_, kk_, a_) async16(Ab + (size_t)(a_) * 64 * K + (kk_), (buf_) + (a_) * 4096 + dW)
#define ISSUE_B(buf_, kk_, c_) async16(Bb + (size_t)(c_) * 64 * K + (kk_), (buf_) + (c_) * 4096 + dW)

    f4v acc[4][6];
    #pragma unroll
    for (int mi = 0; mi < 4; mi++)
        #pragma unroll
        for (int ni = 0; ni < 6; ni++) acc[mi][ni] = 0;

    // ---- prologue: A(0)->a0 (4), B(0)->b0 (3), A(1)->a1 (4); FIFO order matters ----
    #pragma unroll
    for (int a = 0; a < 4; a++) ISSUE_A(a0, 0, a);
    #pragma unroll
    for (int c = 0; c < 3; c++) ISSUE_B(b0, 0, c);
    #pragma unroll
    for (int a = 0; a < 4; a++) ISSUE_A(a1, 64, a);
    asm volatile("s_waitcnt vmcnt(4)" ::: "memory");   // tile 0 landed, A(1) in flight
    asm volatile("s_barrier" ::: "memory");

    for (int t = 0; t < 16; ++t) {
        const int kB = (t + 1) * 64;
        const int kA = (t + 2) * 64;
        s8v af[4][2], bf[2][2];

        // phase 0: read all A + B n0,n1; issue B(t+1)
        RD_A4(a0)
        RD_B2(b0, 0)
        if (t < 15) {
            ISSUE_B(b1, kB, 0);
            ISSUE_B(b1, kB, 1);
            ISSUE_B(b1, kB, 2);
        }
        asm volatile("s_barrier" ::: "memory");
        __builtin_amdgcn_s_setprio(1);
        MFMA16(0)
        __builtin_amdgcn_s_setprio(0);
        asm volatile("s_barrier" ::: "memory");

        // phase 1: read B n2,n3; issue A(t+2) first half
        RD_B2(b0, 2)
        if (t < 14) {
            ISSUE_A(a2, kA, 0);
            ISSUE_A(a2, kA, 1);
        }
        asm volatile("s_barrier" ::: "memory");
        __builtin_amdgcn_s_setprio(1);
        MFMA16(2)
        __builtin_amdgcn_s_setprio(0);
        asm volatile("s_barrier" ::: "memory");

        // phase 2: read B n4,n5; issue A(t+2) second half
        RD_B2(b0, 4)
        if (t < 14) {
            ISSUE_A(a2, kA, 2);
            ISSUE_A(a2, kA, 3);
        }
        asm volatile("s_barrier" ::: "memory");
        __builtin_amdgcn_s_setprio(1);
        MFMA16(4)
        __builtin_amdgcn_s_setprio(0);

        if (t < 14)       asm volatile("s_waitcnt vmcnt(4)" ::: "memory");
        else if (t == 14) asm volatile("s_waitcnt vmcnt(0)" ::: "memory");
        asm volatile("s_barrier" ::: "memory");

        ushort* ta = a0; a0 = a1; a1 = a2; a2 = ta;
        ushort* tb = b0; b0 = b1; b1 = tb;
    }

    // ---- epilogue: per 16-col fragment, z = col>>10 is wave-uniform ----
    #pragma unroll
    for (int mi = 0; mi < 4; mi++)
        #pragma unroll
        for (int ni = 0; ni < 6; ni++) {
            int row = m0 + wm + mi * 16 + quad * 4;
            int col = n0 + wn + ni * 16 + l16;
            int z = col >> 10, cz = col & 1023;
            f4v v = acc[mi][ni];
            if (z < 2) {
                ushort* C = (z == 0) ? q : k;
                #pragma unroll
                for (int rr = 0; rr < 4; rr++)
                    C[(size_t)(row + rr) * 1024 + cz] = f2b(v[rr]);
            } else {
                int b = row >> 11, tok = row & 2047;
                ushort4 pk;
                pk.x = f2b(v[0]); pk.y = f2b(v[1]); pk.z = f2b(v[2]); pk.w = f2b(v[3]);
                *(ushort4*)&vt[(size_t)b * (1024u * 2048u) + (size_t)cz * 2048 + tok] = pk;
            }
        }
#undef ISSUE_A
#undef ISSUE_B
}

// ---------------- E = exp(scale * Q K^T) (bf16, masked), + row sums ----------------
// Same 256x192/144KiB/3-phase pipeline as gemm_qkv (K=1024, NT=16). Triangle tiled
// at BN=192: row-tile mt (256 rows) needs ceil(4(mt+1)/3) n-tiles -> 51/batch,
// 204 blocks total (single ~80%-fill round). Coverage: NT(mt)*192 >= 256(mt+1), so
// every E element gemm_pv reads is written (zeros above diagonal). Fragments with
// colbase >= 2048 are skipped (their K-rows were garbage, masked anyway).
__global__ __launch_bounds__(512, 2) void sgemm_qk(const ushort* __restrict__ Q,
                                                   const ushort* __restrict__ Km,
                                                   ushort* __restrict__ E,
                                                   float* __restrict__ l) {
    constexpr int K = 1024;
    extern __shared__ ushort lds[];

    // bijective XCD swizzle for 204 = 8*25+4: xcd<4 get 26 blocks, xcd>=4 get 25.
    const int L = blockIdx.x;
    const int xcd = L & 7, i = L >> 3;
    const int t = (xcd < 4) ? (xcd * 26 + i) : (104 + (xcd - 4) * 25 + i);
    const int b = t / 51;
    int tt = t - b * 51;
    int mt = 0;
    for (;; mt++) {                      // cnt(mt) = ceil(4(mt+1)/3): 2,3,4,6,7,8,10,11
        int c = (4 * (mt + 1) + 2) / 3;
        if (tt < c) break;
        tt -= c;
    }
    const int nt = tt;
    const int m0 = mt * 256, n0 = nt * 192;
    const ushort* A  = Q  + (size_t)b * 2048 * 1024;
    const ushort* Bt = Km + (size_t)b * 2048 * 1024;
    ushort* Cb = E + (size_t)b * 2048 * 2048;
    float* lb = l + (size_t)b * 2048;

    const int tid = threadIdx.x;
    const int w = tid >> 6, lane = tid & 63, quad = lane >> 4, l16 = lane & 15;
    const int wm = (w >> 1) * 64, wn = (w & 1) * 96;

    ushort* a0 = lds;
    ushort* a1 = lds + 16384;
    ushort* a2 = lds + 32768;
    ushort* b0 = lds + 49152;
    ushort* b1 = lds + 61440;

    const int lr = lane >> 3;
    const int lc8 = (lane & 7) ^ lr;
    const ushort* Ab = A  + (size_t)(m0 + w * 8 + lr) * K + lc8 * 8;
    const ushort* Bb = Bt + (size_t)(n0 + w * 8 + lr) * K + lc8 * 8;
    const int dW = w * 512;

#define ISSUE_A(buf_, kk_, a_) async16(Ab + (size_t)(a_) * 64 * K + (kk_), (buf_) + (a_) * 4096 + dW)
#define ISSUE_B(buf_, kk_, c_) async16(Bb + (size_t)(c_) * 64 * K + (kk_), (buf_) + (c_) * 4096 + dW)

    f4v acc[4][6];
    #pragma unroll
    for (int mi = 0; mi < 4; mi++)
        #pragma unroll
        for (int ni = 0; ni < 6; ni++) acc[mi][ni] = 0;

    #pragma unroll
    for (int a = 0; a < 4; a++) ISSUE_A(a0, 0, a);
    #pragma unroll
    for (int c = 0; c < 3; c++) ISSUE_B(b0, 0, c);
    #pragma unroll
    for (int a = 0; a < 4; a++) ISSUE_A(a1, 64, a);
    asm volatile("s_waitcnt vmcnt(4)" ::: "memory");
    asm volatile("s_barrier" ::: "memory");

    for (int tk = 0; tk < 16; ++tk) {
        const int kB = (tk + 1) * 64;
        const int kA = (tk + 2) * 64;
        s8v af[4][2], bf[2][2];

        RD_A4(a0)
        RD_B2(b0, 0)
        if (tk < 15) {
            ISSUE_B(b1, kB, 0);
            ISSUE_B(b1, kB, 1);
            ISSUE_B(b1, kB, 2);
        }
        asm volatile("s_barrier" ::: "memory");
        __builtin_amdgcn_s_setprio(1);
        MFMA16(0)
        __builtin_amdgcn_s_setprio(0);
        asm volatile("s_barrier" ::: "memory");

        RD_B2(b0, 2)
        if (tk < 14) {
            ISSUE_A(a2, kA, 0);
            ISSUE_A(a2, kA, 1);
        }
        asm volatile("s_barrier" ::: "memory");
        __builtin_amdgcn_s_setprio(1);
        MFMA16(2)
        __builtin_amdgcn_s_setprio(0);
        asm volatile("s_barrier" ::: "memory");

        RD_B2(b0, 4)
        if (tk < 14) {
            ISSUE_A(a2, kA, 2);
            ISSUE_A(a2, kA, 3);
        }
        asm volatile("s_barrier" ::: "memory");
        __builtin_amdgcn_s_setprio(1);
        MFMA16(4)
        __builtin_amdgcn_s_setprio(0);

        if (tk < 14)       asm volatile("s_waitcnt vmcnt(4)" ::: "memory");
        else if (tk == 14) asm volatile("s_waitcnt vmcnt(0)" ::: "memory");
        asm volatile("s_barrier" ::: "memory");

        ushort* ta = a0; a0 = a1; a1 = a2; a2 = ta;
        ushort* tb = b0; b0 = b1; b1 = tb;
    }

    // ---- epilogue: exp + mask + store + per-row partial sums ----
    #pragma unroll
    for (int mi = 0; mi < 4; mi++) {
        float rs[4] = {0.f, 0.f, 0.f, 0.f};
        #pragma unroll
        for (int ni = 0; ni < 6; ni++) {
            const int colbase = n0 + wn + ni * 16;
            if (colbase >= 2048) continue;          // wave-uniform OOB guard
            const int col = colbase + l16;
            f4v v = acc[mi][ni];
            #pragma unroll
            for (int rr = 0; rr < 4; rr++) {
                const int row = m0 + wm + mi * 16 + quad * 4 + rr;
                float e = (col <= row) ? __expf(v[rr] * 0.03125f) : 0.f;
                ushort eb = f2b(e);
                Cb[(size_t)row * 2048 + col] = eb;
                rs[rr] += b2f(eb);
            }
        }
        #pragma unroll
        for (int rr = 0; rr < 4; rr++) {
            float s = rs[rr];
            s += __shfl_xor(s, 1);
            s += __shfl_xor(s, 2);
            s += __shfl_xor(s, 4);
            s += __shfl_xor(s, 8);
            if (l16 == 0)
                atomicAdd(&lb[m0 + wm + mi * 16 + quad * 4 + rr], s);
        }
    }
#undef ISSUE_A
#undef ISSUE_B
}

// ---------------- O += (E_half @ V) / l : split-K, LPT-ordered pieces ----------------
// Every (b, mt, nt) 256x128 tile is split into 2 K-halves of NTh = 2(mt+1) K-tiles.
// 512 pieces enumerated DESCENDING by length (group g: mt = 7-g, length 16..2 K-tiles);
// HW greedy dispatch = LPT scheduling; lengths pair exactly (16+2, 14+4, 12+6, 10+8)
// -> every CU gets 18 K-tiles, makespan ~35 us (was 62 us with whole-tile blocks).
// Each half divides its partial by l[row] (division distributes over K-split) and
// atomicAdds into pre-zeroed fp32 Out. Same 3-deep/2-deep counted-vmcnt loop; the
// half's K-offset K0 folds into the Ab/Bb base pointers.
__global__ __launch_bounds__(512, 2) void gemm_pv(const ushort* __restrict__ Em,
                                                  const ushort* __restrict__ Vt,
                                                  const float* __restrict__ l,
                                                  float* __restrict__ Out) {
    extern __shared__ ushort lds[];
    const int p = blockIdx.x;                       // 512 pieces, descending length
    const int g = p >> 6;                           // 0..7
    const int r = p & 63;
    const int b = r >> 4;                           // 0..3
    const int h = (r >> 3) & 1;                     // K-half
    const int nt = r & 7;
    const int mt = 7 - g;
    const int NTh = 2 * (mt + 1);                   // K-tiles in this half (16..2)
    const int K0 = h * NTh * 64;                    // absolute k start of this half
    const int m0 = mt * 256, n0 = nt * 128;
    const ushort* A  = Em + (size_t)b * 2048 * 2048;
    const ushort* Bt = Vt + (size_t)b * 1024 * 2048;
    const float* lb = l + (size_t)b * 2048;
    float* C = Out + (size_t)b * 2048 * 1024;

    const int tid = threadIdx.x;
    const int w = tid >> 6, lane = tid & 63, quad = lane >> 4, l16 = lane & 15;
    const int wm = (w >> 1) * 64, wn = (w & 1) * 64;

    ushort* a0 = lds;                // A [256][64] = 16384 ushorts per buffer
    ushort* a1 = lds + 16384;
    ushort* a2 = lds + 32768;
    ushort* b0 = lds + 49152;        // B [128][64] = 8192 ushorts per buffer
    ushort* b1 = lds + 57344;        // total 65536 ushorts = 128 KiB

    const int lr = lane >> 3;
    const int lc8 = (lane & 7) ^ lr;
    const ushort* Ab = A  + (size_t)(m0 + w * 8 + lr) * 2048 + K0 + lc8 * 8;
    const ushort* Bb = Bt + (size_t)(n0 + w * 8 + lr) * 2048 + K0 + lc8 * 8;
    const int dW = w * 512;

#define ISSUE_A(buf_, kk_, a_) async16(Ab + (size_t)(a_) * 64 * 2048 + (kk_), (buf_) + (a_) * 4096 + dW)
#define ISSUE_B(buf_, kk_, c_) async16(Bb + (size_t)(c_) * 64 * 2048 + (kk_), (buf_) + (c_) * 4096 + dW)

    f4v acc[4][4];
    #pragma unroll
    for (int mi = 0; mi < 4; mi++)
        #pragma unroll
        for (int ni = 0; ni < 4; ni++) acc[mi][ni] = 0;

    // prologue: A(0) (4), B(0) (2), A(1) (4)  [NTh >= 2 always]
    #pragma unroll
    for (int a = 0; a < 4; a++) ISSUE_A(a0, 0, a);
    #pragma unroll
    for (int c = 0; c < 2; c++) ISSUE_B(b0, 0, c);
    #pragma unroll
    for (int a = 0; a < 4; a++) ISSUE_A(a1, 64, a);
    asm volatile("s_waitcnt vmcnt(4)" ::: "memory");
    asm volatile("s_barrier" ::: "memory");

    for (int tk = 0; tk < NTh; ++tk) {
        const int kB = (tk + 1) * 64;
        const int kA = (tk + 2) * 64;
        s8v af[4][2], bf[2][2];

        // phase 0: read all A + B n0,n1; issue B(t+1) x2 then A(t+2) x2
        RD_A4(a0)
        RD_B2(b0, 0)
        if (tk < NTh - 1) {
            ISSUE_B(b1, kB, 0);
            ISSUE_B(b1, kB, 1);
        }
        if (tk < NTh - 2) {
            ISSUE_A(a2, kA, 0);
            ISSUE_A(a2, kA, 1);
        }
        asm volatile("s_barrier" ::: "memory");
        __builtin_amdgcn_s_setprio(1);
        MFMA16(0)
        __builtin_amdgcn_s_setprio(0);
        asm volatile("s_barrier" ::: "memory");

        // phase 1: read B n2,n3; issue A(t+2) x2
        RD_B2(b0, 2)
        if (tk < NTh - 2) {
            ISSUE_A(a2, kA, 2);
            ISSUE_A(a2, kA, 3);
        }
        asm volatile("s_barrier" ::: "memory");
        __builtin_amdgcn_s_setprio(1);
        MFMA16(2)
        __builtin_amdgcn_s_setprio(0);

        if (tk < NTh - 2)       asm volatile("s_waitcnt vmcnt(4)" ::: "memory");
        else if (tk == NTh - 2) asm volatile("s_waitcnt vmcnt(0)" ::: "memory");
        asm volatile("s_barrier" ::: "memory");

        ushort* ta = a0; a0 = a1; a1 = a2; a2 = ta;
        ushort* tb = b0; b0 = b1; b1 = tb;
    }

    // ---- epilogue: divide partial by row sums, atomic-accumulate fp32 ----
    #pragma unroll
    for (int mi = 0; mi < 4; mi++) {
        const int row = m0 + wm + mi * 16 + quad * 4;
        float inv[4];
        #pragma unroll
        for (int rr = 0; rr < 4; rr++) inv[rr] = 1.f / lb[row + rr];
        #pragma unroll
        for (int ni = 0; ni < 4; ni++) {
            const int col = n0 + wn + ni * 16 + l16;
            f4v v = acc[mi][ni];
            #pragma unroll
            for (int rr = 0; rr < 4; rr++)
                atomicAdd(&C[(size_t)(row + rr) * 1024 + col], v[rr] * inv[rr]);
        }
    }
#undef ISSUE_A
#undef ISSUE_B
}

extern "C" void kernel_launch(void* const* d_in, const int* in_sizes, int n_in,
                              void* d_out, int out_size, void* d_ws, size_t ws_size,
                              hipStream_t stream) {
    const float* x  = (const float*)d_in[0];
    const float* Wq = (const float*)d_in[1];
    const float* Wk = (const float*)d_in[2];
    const float* Wv = (const float*)d_in[3];
    float* out = (float*)d_out;

    static bool init = false;
    if (!init) {
        hipFuncSetAttribute(reinterpret_cast<const void*>(gemm_qkv),
                            hipFuncAttributeMaxDynamicSharedMemorySize, 147456);
        hipFuncSetAttribute(reinterpret_cast<const void*>(sgemm_qk),
                            hipFuncAttributeMaxDynamicSharedMemorySize, 147456);
        hipFuncSetAttribute(reinterpret_cast<const void*>(gemm_pv),
                            hipFuncAttributeMaxDynamicSharedMemorySize, 131072);
        init = true;
    }

    char* ws = (char*)d_ws;
    // workspace layout (MiB offsets), total ~103 MiB:
    //   xb @   0 : 16  bf16 x [8192][1024]
    //   wt @  16 :  6  bf16 W^T x3 [out][in]
    //   q  @  22 : 16  bf16 [8192][1024]
    //   k  @  38 : 16  bf16 [8192][1024]
    //   vt @  54 : 16  bf16 Vt[b][1024][2048]
    //   E  @  70 : 32  bf16 exp(S)[b][2048][2048] (unnormalized, masked)
    //   l  @ 102 : 32 KB fp32 row sums [4][2048]
    const size_t MiB = 1u << 20;
    ushort* xb = (ushort*)(ws);
    ushort* wt = (ushort*)(ws + 16 * MiB);
    ushort* q  = (ushort*)(ws + 22 * MiB);
    ushort* k  = (ushort*)(ws + 38 * MiB);
    ushort* vt = (ushort*)(ws + 54 * MiB);
    ushort* E  = (ushort*)(ws + 70 * MiB);
    float*  l  = (float*)(ws + 102 * MiB);

    cast_f32_bf16<<<(8192 * 1024 / 4) / 256, 256, 0, stream>>>(x, xb, l, out, 8192 * 1024 / 4);
    transpose_cast<<<dim3(32, 32, 3), dim3(32, 8), 0, stream>>>(Wq, Wk, Wv, wt);

    gemm_qkv<<<512, 512, 147456, stream>>>(xb, wt, q, k, vt);
    sgemm_qk<<<204, 512, 147456, stream>>>(q, k, E, l);
    gemm_pv<<<512, 512, 131072, stream>>>(E, vt, l, out);
}

// Round 5
// 208.302 us; speedup vs baseline: 1.1954x; 1.1954x over previous
//
#include <hip/hip_runtime.h>

typedef float  f4v  __attribute__((ext_vector_type(4)));
typedef short  s8v  __attribute__((ext_vector_type(8)));

// fp32 -> bf16 round-to-nearest-even
__device__ __forceinline__ ushort f2b(float f) {
    union { float f; unsigned int u; } v; v.f = f;
    unsigned int u = v.u;
    u += 0x7fffu + ((u >> 16) & 1u);
    return (ushort)(u >> 16);
}
__device__ __forceinline__ float b2f(ushort u) {
    union { unsigned int u; float f; } v; v.u = ((unsigned int)u) << 16;
    return v.f;
}

// async global->LDS, 16B per lane. ldsp MUST be wave-uniform; HW writes
// lane i's 16B at ldsp + i*16 (no per-lane scatter, no padding allowed).
__device__ __forceinline__ void async16(const ushort* g, ushort* ldsp) {
    __builtin_amdgcn_global_load_lds(
        (const __attribute__((address_space(1))) unsigned int*)g,
        (__attribute__((address_space(3))) unsigned int*)ldsp, 16, 0, 0);
}

// ---------------- cast x (fp32) -> bf16 + zero the row-sum accumulator ----------------
__global__ __launch_bounds__(256) void cast_f32_bf16(const float* __restrict__ in,
                                                     ushort* __restrict__ out,
                                                     float* __restrict__ l, int n4) {
    int i = blockIdx.x * 256 + threadIdx.x;
    if (i < 8192) l[i] = 0.f;   // 4 batches x 2048 rows
    if (i < n4) {
        float4 f = ((const float4*)in)[i];
        ushort4 o;
        o.x = f2b(f.x); o.y = f2b(f.y); o.z = f2b(f.z); o.w = f2b(f.w);
        ((ushort4*)out)[i] = o;
    }
}

// ---------------- transpose W [1024x1024] fp32 -> Wt bf16 [out][in] ----------------
__global__ __launch_bounds__(256) void transpose_cast(const float* __restrict__ w0,
                                                      const float* __restrict__ w1,
                                                      const float* __restrict__ w2,
                                                      ushort* __restrict__ out) {
    __shared__ float tile[32][33];
    const float* W = (blockIdx.z == 0) ? w0 : (blockIdx.z == 1 ? w1 : w2);
    ushort* O = out + (size_t)blockIdx.z * (1024u * 1024u);
    int x0 = blockIdx.x * 32, y0 = blockIdx.y * 32;
    int tx = threadIdx.x, ty = threadIdx.y;
    for (int i = 0; i < 4; i++)
        tile[ty + i * 8][tx] = W[(size_t)(y0 + ty + i * 8) * 1024 + x0 + tx];
    __syncthreads();
    for (int i = 0; i < 4; i++)
        O[(size_t)(x0 + ty + i * 8) * 1024 + y0 + tx] = f2b(tile[tx][ty + i * 8]);
}

// ===================== shared pipeline macros (counted-vmcnt) =====================
// Both-sides XOR swizzle: global source col pre-swizzled (lc8 = (lane&7)^lr, row%8==lr),
// ds_read col swizzled by ^(l16&7). Linear LDS dest for global_load_lds.

#define RD_A4(buf_)                                                                   \
    _Pragma("unroll") for (int mi = 0; mi < 4; mi++)                                  \
    _Pragma("unroll") for (int s = 0; s < 2; s++)                                     \
        af[mi][s] = *(const s8v*)&(buf_)[(wm + mi * 16 + l16) * 64 +                  \
                                         (((s * 4 + quad) ^ (l16 & 7)) * 8)];

#define RD_B2(buf_, NI0_)                                                             \
    _Pragma("unroll") for (int j = 0; j < 2; j++)                                     \
    _Pragma("unroll") for (int s = 0; s < 2; s++)                                     \
        bf[j][s] = *(const s8v*)&(buf_)[(wn + ((NI0_) + j) * 16 + l16) * 64 +         \
                                        (((s * 4 + quad) ^ (l16 & 7)) * 8)];

#define MFMA16(NI0_)                                                                  \
    _Pragma("unroll") for (int mi = 0; mi < 4; mi++)                                  \
    _Pragma("unroll") for (int j = 0; j < 2; j++)                                     \
    _Pragma("unroll") for (int s = 0; s < 2; s++)                                     \
        acc[mi][(NI0_) + j] = __builtin_amdgcn_mfma_f32_16x16x32_bf16(                \
            af[mi][s], bf[j][s], acc[mi][(NI0_) + j], 0, 0, 0);

// ---------------- fused QKV projection: 256x192 tile, counted-vmcnt pipeline --------
// Grid 32m x 16n = 512 blocks = exactly 2 full CU-rounds. 8 waves 4m x 2n ->
// wave tile 64x96 (acc[4][6]). LDS 144 KiB: A 3-deep [256][64], B 2-deep [192][64].
// 3 phases x 16 MFMA per K-tile; boundary vmcnt(4) leaves A(t+2) in flight.
__global__ __launch_bounds__(512, 2) void gemm_qkv(const ushort* __restrict__ A,
                                                   const ushort* __restrict__ Wt,
                                                   ushort* __restrict__ q,
                                                   ushort* __restrict__ k,
                                                   ushort* __restrict__ vt) {
    constexpr int K = 1024;
    extern __shared__ ushort lds[];

    const int L = blockIdx.x;
    const int xcd = L & 7, idx = L >> 3;            // idx 0..63
    const int ci = xcd >> 1, cj = xcd & 1;          // chunk grid 4x2 over 32m x 16n
    const int mo = idx >> 3, no = idx & 7;
    const int m0 = (ci * 8 + mo) * 256;             // 0..8191
    const int n0 = (cj * 8 + no) * 192;             // 0..3071 (spans q|k|v columns)

    const int tid = threadIdx.x;
    const int w = tid >> 6, lane = tid & 63, quad = lane >> 4, l16 = lane & 15;
    const int wm = (w >> 1) * 64, wn = (w & 1) * 96;

    ushort* a0 = lds;                // A [256][64] = 16384 ushorts per buffer
    ushort* a1 = lds + 16384;
    ushort* a2 = lds + 32768;
    ushort* b0 = lds + 49152;        // B [192][64] = 12288 ushorts per buffer
    ushort* b1 = lds + 61440;        // total 73728 ushorts = 144 KiB

    const int lr = lane >> 3;
    const int lc8 = (lane & 7) ^ lr;
    const ushort* Ab = A  + (size_t)(m0 + w * 8 + lr) * K + lc8 * 8;
    const ushort* Bb = Wt + (size_t)(n0 + w * 8 + lr) * K + lc8 * 8;  // Wt = [3072][1024]
    const int dW = w * 512;

#define ISSUE_A(buf_, kk_, a_) async16(Ab + (size_t)(a_) * 64 * K + (kk_), (buf_) + (a_) * 4096 + dW)
#define ISSUE_B(buf_, kk_, c_) async16(Bb + (size_t)(c_) * 64 * K + (kk_), (buf_) + (c_) * 4096 + dW)

    f4v acc[4][6];
    #pragma unroll
    for (int mi = 0; mi < 4; mi++)
        #pragma unroll
        for (int ni = 0; ni < 6; ni++) acc[mi][ni] = 0;

    // ---- prologue: A(0)->a0 (4), B(0)->b0 (3), A(1)->a1 (4); FIFO order matters ----
    #pragma unroll
    for (int a = 0; a < 4; a++) ISSUE_A(a0, 0, a);
    #pragma unroll
    for (int c = 0; c < 3; c++) ISSUE_B(b0, 0, c);
    #pragma unroll
    for (int a = 0; a < 4; a++) ISSUE_A(a1, 64, a);
    asm volatile("s_waitcnt vmcnt(4)" ::: "memory");   // tile 0 landed, A(1) in flight
    asm volatile("s_barrier" ::: "memory");

    for (int t = 0; t < 16; ++t) {
        const int kB = (t + 1) * 64;
        const int kA = (t + 2) * 64;
        s8v af[4][2], bf[2][2];

        // phase 0: read all A + B n0,n1; issue B(t+1)
        RD_A4(a0)
        RD_B2(b0, 0)
        if (t < 15) {
            ISSUE_B(b1, kB, 0);
            ISSUE_B(b1, kB, 1);
            ISSUE_B(b1, kB, 2);
        }
        asm volatile("s_barrier" ::: "memory");
        __builtin_amdgcn_s_setprio(1);
        MFMA16(0)
        __builtin_amdgcn_s_setprio(0);
        asm volatile("s_barrier" ::: "memory");

        // phase 1: read B n2,n3; issue A(t+2) first half
        RD_B2(b0, 2)
        if (t < 14) {
            ISSUE_A(a2, kA, 0);
            ISSUE_A(a2, kA, 1);
        }
        asm volatile("s_barrier" ::: "memory");
        __builtin_amdgcn_s_setprio(1);
        MFMA16(2)
        __builtin_amdgcn_s_setprio(0);
        asm volatile("s_barrier" ::: "memory");

        // phase 2: read B n4,n5; issue A(t+2) second half
        RD_B2(b0, 4)
        if (t < 14) {
            ISSUE_A(a2, kA, 2);
            ISSUE_A(a2, kA, 3);
        }
        asm volatile("s_barrier" ::: "memory");
        __builtin_amdgcn_s_setprio(1);
        MFMA16(4)
        __builtin_amdgcn_s_setprio(0);

        if (t < 14)       asm volatile("s_waitcnt vmcnt(4)" ::: "memory");
        else if (t == 14) asm volatile("s_waitcnt vmcnt(0)" ::: "memory");
        asm volatile("s_barrier" ::: "memory");

        ushort* ta = a0; a0 = a1; a1 = a2; a2 = ta;
        ushort* tb = b0; b0 = b1; b1 = tb;
    }

    // ---- epilogue: per 16-col fragment, z = col>>10 is wave-uniform ----
    #pragma unroll
    for (int mi = 0; mi < 4; mi++)
        #pragma unroll
        for (int ni = 0; ni < 6; ni++) {
            int row = m0 + wm + mi * 16 + quad * 4;
            int col = n0 + wn + ni * 16 + l16;
            int z = col >> 10, cz = col & 1023;
            f4v v = acc[mi][ni];
            if (z < 2) {
                ushort* C = (z == 0) ? q : k;
                #pragma unroll
                for (int rr = 0; rr < 4; rr++)
                    C[(size_t)(row + rr) * 1024 + cz] = f2b(v[rr]);
            } else {
                int b = row >> 11, tok = row & 2047;
                ushort4 pk;
                pk.x = f2b(v[0]); pk.y = f2b(v[1]); pk.z = f2b(v[2]); pk.w = f2b(v[3]);
                *(ushort4*)&vt[(size_t)b * (1024u * 2048u) + (size_t)cz * 2048 + tok] = pk;
            }
        }
#undef ISSUE_A
#undef ISSUE_B
}

// ---------------- E = exp(scale * Q K^T) (bf16, masked), + row sums ----------------
// Same 256x192/144KiB/3-phase pipeline as gemm_qkv (K=1024, NT=16). Triangle tiled
// at BN=192: row-tile mt (256 rows) needs ceil(4(mt+1)/3) n-tiles -> 51/batch,
// 204 blocks total (single ~80%-fill round). Coverage: NT(mt)*192 >= 256(mt+1), so
// every E element gemm_pv reads is written (zeros above diagonal). Fragments with
// colbase >= 2048 are skipped (their K-rows were garbage, masked anyway).
__global__ __launch_bounds__(512, 2) void sgemm_qk(const ushort* __restrict__ Q,
                                                   const ushort* __restrict__ Km,
                                                   ushort* __restrict__ E,
                                                   float* __restrict__ l) {
    constexpr int K = 1024;
    extern __shared__ ushort lds[];

    // bijective XCD swizzle for 204 = 8*25+4: xcd<4 get 26 blocks, xcd>=4 get 25.
    const int L = blockIdx.x;
    const int xcd = L & 7, i = L >> 3;
    const int t = (xcd < 4) ? (xcd * 26 + i) : (104 + (xcd - 4) * 25 + i);
    const int b = t / 51;
    int tt = t - b * 51;
    int mt = 0;
    for (;; mt++) {                      // cnt(mt) = ceil(4(mt+1)/3): 2,3,4,6,7,8,10,11
        int c = (4 * (mt + 1) + 2) / 3;
        if (tt < c) break;
        tt -= c;
    }
    const int nt = tt;
    const int m0 = mt * 256, n0 = nt * 192;
    const ushort* A  = Q  + (size_t)b * 2048 * 1024;
    const ushort* Bt = Km + (size_t)b * 2048 * 1024;
    ushort* Cb = E + (size_t)b * 2048 * 2048;
    float* lb = l + (size_t)b * 2048;

    const int tid = threadIdx.x;
    const int w = tid >> 6, lane = tid & 63, quad = lane >> 4, l16 = lane & 15;
    const int wm = (w >> 1) * 64, wn = (w & 1) * 96;

    ushort* a0 = lds;
    ushort* a1 = lds + 16384;
    ushort* a2 = lds + 32768;
    ushort* b0 = lds + 49152;
    ushort* b1 = lds + 61440;

    const int lr = lane >> 3;
    const int lc8 = (lane & 7) ^ lr;
    const ushort* Ab = A  + (size_t)(m0 + w * 8 + lr) * K + lc8 * 8;
    const ushort* Bb = Bt + (size_t)(n0 + w * 8 + lr) * K + lc8 * 8;
    const int dW = w * 512;

#define ISSUE_A(buf_, kk_, a_) async16(Ab + (size_t)(a_) * 64 * K + (kk_), (buf_) + (a_) * 4096 + dW)
#define ISSUE_B(buf_, kk_, c_) async16(Bb + (size_t)(c_) * 64 * K + (kk_), (buf_) + (c_) * 4096 + dW)

    f4v acc[4][6];
    #pragma unroll
    for (int mi = 0; mi < 4; mi++)
        #pragma unroll
        for (int ni = 0; ni < 6; ni++) acc[mi][ni] = 0;

    #pragma unroll
    for (int a = 0; a < 4; a++) ISSUE_A(a0, 0, a);
    #pragma unroll
    for (int c = 0; c < 3; c++) ISSUE_B(b0, 0, c);
    #pragma unroll
    for (int a = 0; a < 4; a++) ISSUE_A(a1, 64, a);
    asm volatile("s_waitcnt vmcnt(4)" ::: "memory");
    asm volatile("s_barrier" ::: "memory");

    for (int tk = 0; tk < 16; ++tk) {
        const int kB = (tk + 1) * 64;
        const int kA = (tk + 2) * 64;
        s8v af[4][2], bf[2][2];

        RD_A4(a0)
        RD_B2(b0, 0)
        if (tk < 15) {
            ISSUE_B(b1, kB, 0);
            ISSUE_B(b1, kB, 1);
            ISSUE_B(b1, kB, 2);
        }
        asm volatile("s_barrier" ::: "memory");
        __builtin_amdgcn_s_setprio(1);
        MFMA16(0)
        __builtin_amdgcn_s_setprio(0);
        asm volatile("s_barrier" ::: "memory");

        RD_B2(b0, 2)
        if (tk < 14) {
            ISSUE_A(a2, kA, 0);
            ISSUE_A(a2, kA, 1);
        }
        asm volatile("s_barrier" ::: "memory");
        __builtin_amdgcn_s_setprio(1);
        MFMA16(2)
        __builtin_amdgcn_s_setprio(0);
        asm volatile("s_barrier" ::: "memory");

        RD_B2(b0, 4)
        if (tk < 14) {
            ISSUE_A(a2, kA, 2);
            ISSUE_A(a2, kA, 3);
        }
        asm volatile("s_barrier" ::: "memory");
        __builtin_amdgcn_s_setprio(1);
        MFMA16(4)
        __builtin_amdgcn_s_setprio(0);

        if (tk < 14)       asm volatile("s_waitcnt vmcnt(4)" ::: "memory");
        else if (tk == 14) asm volatile("s_waitcnt vmcnt(0)" ::: "memory");
        asm volatile("s_barrier" ::: "memory");

        ushort* ta = a0; a0 = a1; a1 = a2; a2 = ta;
        ushort* tb = b0; b0 = b1; b1 = tb;
    }

    // ---- epilogue: exp + mask + store + per-row partial sums ----
    #pragma unroll
    for (int mi = 0; mi < 4; mi++) {
        float rs[4] = {0.f, 0.f, 0.f, 0.f};
        #pragma unroll
        for (int ni = 0; ni < 6; ni++) {
            const int colbase = n0 + wn + ni * 16;
            if (colbase >= 2048) continue;          // wave-uniform OOB guard
            const int col = colbase + l16;
            f4v v = acc[mi][ni];
            #pragma unroll
            for (int rr = 0; rr < 4; rr++) {
                const int row = m0 + wm + mi * 16 + quad * 4 + rr;
                float e = (col <= row) ? __expf(v[rr] * 0.03125f) : 0.f;
                ushort eb = f2b(e);
                Cb[(size_t)row * 2048 + col] = eb;
                rs[rr] += b2f(eb);
            }
        }
        #pragma unroll
        for (int rr = 0; rr < 4; rr++) {
            float s = rs[rr];
            s += __shfl_xor(s, 1);
            s += __shfl_xor(s, 2);
            s += __shfl_xor(s, 4);
            s += __shfl_xor(s, 8);
            if (l16 == 0)
                atomicAdd(&lb[m0 + wm + mi * 16 + quad * 4 + rr], s);
        }
    }
#undef ISSUE_A
#undef ISSUE_B
}

// ---------------- O = (E @ V) / l : per-batch [2048x1024] fp32 ----------------
// 128x128 tile, 8 waves 2m x 4n -> wave 64x32 (acc[4][2]); NT = 2(mt+1) K-tiles.
// LDS 80 KiB (A 3-deep + B 2-deep of [128][64]) -> 2 blocks/CU -> ALL 512 blocks
// co-resident; blocks L and L+256 map to mt and 15-mt so each CU's two resident
// blocks total exactly 34 K-tiles (balanced makespan, no atomics, no split-K).
// One phase per K-tile: {read A(8)+B(4); issue B(t+1)x2 + A(t+2)x2; barrier;
// 16 MFMA; boundary vmcnt(2) (A(t+2) stays in flight); barrier}.
__global__ __launch_bounds__(512, 2) void gemm_pv(const ushort* __restrict__ Em,
                                                  const ushort* __restrict__ Vt,
                                                  const float* __restrict__ l,
                                                  float* __restrict__ Out) {
    extern __shared__ ushort lds[];
    const int L = blockIdx.x;                       // 512 blocks
    int p, mt;
    if (L < 256) { p = L;       mt = 15 - (p >> 5); }   // long pieces first
    else         { p = L - 256; mt = (p >> 5); }        // paired short pieces
    const int inner = p & 31;
    const int b = inner >> 3;                       // 0..3
    const int nt = inner & 7;                       // 0..7
    const int m0 = mt * 128, n0 = nt * 128;
    const int NT = 2 * (mt + 1);                    // K-tiles of 64; K = 128(mt+1)
    const ushort* A  = Em + (size_t)b * 2048 * 2048;
    const ushort* Bt = Vt + (size_t)b * 1024 * 2048;
    const float* lb = l + (size_t)b * 2048;
    float* C = Out + (size_t)b * 2048 * 1024;

    const int tid = threadIdx.x;
    const int w = tid >> 6, lane = tid & 63, quad = lane >> 4, l16 = lane & 15;
    const int wm = (w >> 2) * 64, wn = (w & 3) * 32;

    ushort* a0 = lds;                // A [128][64] = 8192 ushorts per buffer
    ushort* a1 = lds + 8192;
    ushort* a2 = lds + 16384;
    ushort* b0 = lds + 24576;        // B [128][64] = 8192 ushorts per buffer
    ushort* b1 = lds + 32768;        // total 40960 ushorts = 80 KiB

    const int lr = lane >> 3;
    const int lc8 = (lane & 7) ^ lr;
    const ushort* Ab = A  + (size_t)(m0 + w * 8 + lr) * 2048 + lc8 * 8;
    const ushort* Bb = Bt + (size_t)(n0 + w * 8 + lr) * 2048 + lc8 * 8;
    const int dW = w * 512;

#define ISSUE_A(buf_, kk_, a_) async16(Ab + (size_t)(a_) * 64 * 2048 + (kk_), (buf_) + (a_) * 4096 + dW)
#define ISSUE_B(buf_, kk_, c_) async16(Bb + (size_t)(c_) * 64 * 2048 + (kk_), (buf_) + (c_) * 4096 + dW)

    f4v acc[4][2];
    #pragma unroll
    for (int mi = 0; mi < 4; mi++)
        #pragma unroll
        for (int ni = 0; ni < 2; ni++) acc[mi][ni] = 0;

    // prologue: A(0) (2), B(0) (2), A(1) (2)  [NT >= 2 always]
    #pragma unroll
    for (int a = 0; a < 2; a++) ISSUE_A(a0, 0, a);
    #pragma unroll
    for (int c = 0; c < 2; c++) ISSUE_B(b0, 0, c);
    #pragma unroll
    for (int a = 0; a < 2; a++) ISSUE_A(a1, 64, a);
    asm volatile("s_waitcnt vmcnt(2)" ::: "memory");   // tile 0 landed, A(1) in flight
    asm volatile("s_barrier" ::: "memory");

    for (int tk = 0; tk < NT; ++tk) {
        const int kB = (tk + 1) * 64;
        const int kA = (tk + 2) * 64;
        s8v af[4][2], bf[2][2];

        RD_A4(a0)
        RD_B2(b0, 0)
        if (tk < NT - 1) {
            ISSUE_B(b1, kB, 0);
            ISSUE_B(b1, kB, 1);
        }
        if (tk < NT - 2) {
            ISSUE_A(a2, kA, 0);
            ISSUE_A(a2, kA, 1);
        }
        asm volatile("s_barrier" ::: "memory");
        __builtin_amdgcn_s_setprio(1);
        MFMA16(0)
        __builtin_amdgcn_s_setprio(0);

        // boundary: drain A(t+1)+B(t+1), leave A(t+2) in flight
        if (tk < NT - 2)       asm volatile("s_waitcnt vmcnt(2)" ::: "memory");
        else if (tk == NT - 2) asm volatile("s_waitcnt vmcnt(0)" ::: "memory");
        asm volatile("s_barrier" ::: "memory");

        ushort* ta = a0; a0 = a1; a1 = a2; a2 = ta;
        ushort* tb = b0; b0 = b1; b1 = tb;
    }

    // ---- epilogue: divide by row sums, plain fp32 stores (tile owns its output) ----
    #pragma unroll
    for (int mi = 0; mi < 4; mi++) {
        const int row = m0 + wm + mi * 16 + quad * 4;
        float inv[4];
        #pragma unroll
        for (int rr = 0; rr < 4; rr++) inv[rr] = 1.f / lb[row + rr];
        #pragma unroll
        for (int ni = 0; ni < 2; ni++) {
            const int col = n0 + wn + ni * 16 + l16;
            f4v v = acc[mi][ni];
            #pragma unroll
            for (int rr = 0; rr < 4; rr++)
                C[(size_t)(row + rr) * 1024 + col] = v[rr] * inv[rr];
        }
    }
#undef ISSUE_A
#undef ISSUE_B
}

extern "C" void kernel_launch(void* const* d_in, const int* in_sizes, int n_in,
                              void* d_out, int out_size, void* d_ws, size_t ws_size,
                              hipStream_t stream) {
    const float* x  = (const float*)d_in[0];
    const float* Wq = (const float*)d_in[1];
    const float* Wk = (const float*)d_in[2];
    const float* Wv = (const float*)d_in[3];
    float* out = (float*)d_out;

    static bool init = false;
    if (!init) {
        hipFuncSetAttribute(reinterpret_cast<const void*>(gemm_qkv),
                            hipFuncAttributeMaxDynamicSharedMemorySize, 147456);
        hipFuncSetAttribute(reinterpret_cast<const void*>(sgemm_qk),
                            hipFuncAttributeMaxDynamicSharedMemorySize, 147456);
        hipFuncSetAttribute(reinterpret_cast<const void*>(gemm_pv),
                            hipFuncAttributeMaxDynamicSharedMemorySize, 81920);
        init = true;
    }

    char* ws = (char*)d_ws;
    // workspace layout (MiB offsets), total ~103 MiB:
    //   xb @   0 : 16  bf16 x [8192][1024]
    //   wt @  16 :  6  bf16 W^T x3 [out][in]
    //   q  @  22 : 16  bf16 [8192][1024]
    //   k  @  38 : 16  bf16 [8192][1024]
    //   vt @  54 : 16  bf16 Vt[b][1024][2048]
    //   E  @  70 : 32  bf16 exp(S)[b][2048][2048] (unnormalized, masked)
    //   l  @ 102 : 32 KB fp32 row sums [4][2048]
    const size_t MiB = 1u << 20;
    ushort* xb = (ushort*)(ws);
    ushort* wt = (ushort*)(ws + 16 * MiB);
    ushort* q  = (ushort*)(ws + 22 * MiB);
    ushort* k  = (ushort*)(ws + 38 * MiB);
    ushort* vt = (ushort*)(ws + 54 * MiB);
    ushort* E  = (ushort*)(ws + 70 * MiB);
    float*  l  = (float*)(ws + 102 * MiB);

    cast_f32_bf16<<<(8192 * 1024 / 4) / 256, 256, 0, stream>>>(x, xb, l, 8192 * 1024 / 4);
    transpose_cast<<<dim3(32, 32, 3), dim3(32, 8), 0, stream>>>(Wq, Wk, Wv, wt);

    gemm_qkv<<<512, 512, 147456, stream>>>(xb, wt, q, k, vt);
    sgemm_qk<<<204, 512, 147456, stream>>>(q, k, E, l);
    gemm_pv<<<512, 512, 81920, stream>>>(E, vt, l, out);
}